// Round 7
// baseline (297.016 us; speedup 1.0000x reference)
//
#include <hip/hip_runtime.h>
#include <hip/hip_bf16.h>

typedef __attribute__((ext_vector_type(8))) short bf16x8;
typedef __attribute__((ext_vector_type(4))) float f32x4;
typedef __attribute__((ext_vector_type(16))) float f32x16;
typedef __attribute__((ext_vector_type(4))) int i32x4;
typedef unsigned short u16;

__device__ __forceinline__ u16 f2bf(float f) {
    __hip_bfloat16 h = __float2bfloat16(f);
    return __builtin_bit_cast(u16, h);
}
__device__ __forceinline__ bf16x8 load8(const u16* p) {
    return *reinterpret_cast<const bf16x8*>(p);
}
__device__ __forceinline__ void gl2lds16(const u16* g, u16* l) {
    __builtin_amdgcn_global_load_lds(
        (const __attribute__((address_space(1))) void*)g,
        (__attribute__((address_space(3))) void*)l, 16, 0, 0);
}
// v_cvt_pk_bf16_f32: low16 = bf16(lo), high16 = bf16(hi)
__device__ __forceinline__ unsigned int cvtpk(float lo, float hi) {
    unsigned int r;
    asm("v_cvt_pk_bf16_f32 %0, %1, %2" : "=v"(r) : "v"(lo), "v"(hi));
    return r;
}

// log2(e)/8: folded into Q so softmax is exp2(s) with no per-element mul
#define QSCALE 0.1803368801111244f

// ---------------------------------------------------------------------------
__global__ __launch_bounds__(256) void cast_f32_bf16(
    const float* __restrict__ src, u16* __restrict__ dst, int n4)
{
    int i = blockIdx.x * blockDim.x + threadIdx.x;
    if (i < n4) {
        float4 f = reinterpret_cast<const float4*>(src)[i];
        ushort4 o;
        o.x = f2bf(f.x); o.y = f2bf(f.y); o.z = f2bf(f.z); o.w = f2bf(f.w);
        reinterpret_cast<ushort4*>(dst)[i] = o;
    }
}

// ---------------------------------------------------------------------------
// m97-style 128x128 GEMM core (bf16, B^T layout W[n][k]).
// ---------------------------------------------------------------------------
#define GEMM128_BODY(EPILOGUE)                                                 \
    __shared__ __align__(16) u16 As[128 * 32];                                 \
    __shared__ __align__(16) u16 Bs[128 * 32];                                 \
    const int t = threadIdx.x;                                                 \
    const int lane = t & 63;                                                   \
    const int wave = t >> 6;                                                   \
    const int quad = lane >> 4;                                                \
    const int lid  = lane & 15;                                                \
    const int wrow = wave & 1;                                                 \
    const int wcol = wave >> 1;                                                \
    const int mtile = blockIdx.x * 128;                                        \
    const int ntile = blockIdx.y * 128;                                        \
    const int srow = t >> 2;                                                   \
    const int scol = (t & 3) * 8;                                              \
    const u16* ga0 = Aptr + (size_t)(mtile + srow) * 1024 + scol;              \
    const u16* ga1 = Aptr + (size_t)(mtile + 64 + srow) * 1024 + scol;         \
    const u16* gb0 = Bptr + (size_t)(ntile + srow) * 1024 + scol;              \
    const u16* gb1 = Bptr + (size_t)(ntile + 64 + srow) * 1024 + scol;         \
    u16* la0 = As + t * 8;                                                     \
    u16* la1 = As + (256 + t) * 8;                                             \
    u16* lb0 = Bs + t * 8;                                                     \
    u16* lb1 = Bs + (256 + t) * 8;                                             \
    f32x4 acc[4][4] = {};                                                      \
    const int aro = wrow * 64 * 32 + quad * 8;                                 \
    const int bro = wcol * 64 * 32 + quad * 8;                                 \
    for (int k0 = 0; k0 < 1024; k0 += 32) {                                    \
        __syncthreads();                                                       \
        gl2lds16(ga0 + k0, la0);                                               \
        gl2lds16(ga1 + k0, la1);                                               \
        gl2lds16(gb0 + k0, lb0);                                               \
        gl2lds16(gb1 + k0, lb1);                                               \
        __syncthreads();                                                       \
        bf16x8 a[4], b[4];                                                     \
        _Pragma("unroll")                                                      \
        for (int i = 0; i < 4; ++i) {                                          \
            a[i] = load8(As + aro + (i * 16 + lid) * 32);                      \
            b[i] = load8(Bs + bro + (i * 16 + lid) * 32);                      \
        }                                                                      \
        _Pragma("unroll")                                                      \
        for (int mi = 0; mi < 4; ++mi)                                         \
            _Pragma("unroll")                                                  \
            for (int ni = 0; ni < 4; ++ni)                                     \
                acc[mi][ni] = __builtin_amdgcn_mfma_f32_16x16x32_bf16(         \
                    a[mi], b[ni], acc[mi][ni], 0, 0, 0);                       \
    }                                                                          \
    EPILOGUE

// ---------------------------------------------------------------------------
// Kernel 1: QKV projection.  Q (pre-scaled by QSCALE), K -> [16][8192][64];
// V transposed -> Vt[16][64][8192].
// ---------------------------------------------------------------------------
__global__ __launch_bounds__(256) void qkv_gemm128(
    const u16* __restrict__ Aptr, const u16* __restrict__ Bptr,
    u16* __restrict__ Q, u16* __restrict__ K, u16* __restrict__ Vt)
{
    GEMM128_BODY(
    _Pragma("unroll")
    for (int mi = 0; mi < 4; ++mi)
        _Pragma("unroll")
        for (int ni = 0; ni < 4; ++ni)
            _Pragma("unroll")
            for (int r = 0; r < 4; ++r) {
                int m = mtile + wrow * 64 + mi * 16 + quad * 4 + r;
                int n = ntile + wcol * 64 + ni * 16 + lid;
                int h = n / 192;
                int rr = n - h * 192;
                int sel = rr >> 6;
                int d = rr & 63;
                float v = acc[mi][ni][r];
                if (sel == 2)
                    Vt[((size_t)h * 64 + d) * 8192 + m] = f2bf(v);
                else if (sel == 0)
                    Q[((size_t)h * 8192 + m) * 64 + d] = f2bf(v * QSCALE);
                else
                    K[((size_t)h * 8192 + m) * 64 + d] = f2bf(v);
            }
    )
}

// ---------------------------------------------------------------------------
// Kernel 3: output projection, fp32 out + bias
// ---------------------------------------------------------------------------
__global__ __launch_bounds__(256) void proj_gemm128(
    const u16* __restrict__ Aptr, const u16* __restrict__ Bptr,
    const float* __restrict__ bias, float* __restrict__ out)
{
    GEMM128_BODY(
    _Pragma("unroll")
    for (int mi = 0; mi < 4; ++mi)
        _Pragma("unroll")
        for (int ni = 0; ni < 4; ++ni)
            _Pragma("unroll")
            for (int r = 0; r < 4; ++r) {
                int m = mtile + wrow * 64 + mi * 16 + quad * 4 + r;
                int n = ntile + wcol * 64 + ni * 16 + lid;
                out[(size_t)m * 1024 + n] = acc[mi][ni][r] + bias[n];
            }
    )
}

// ---------------------------------------------------------------------------
// softmax for one 32-key half: st rows r -> key kgbase + (r&3)+8*(r>>2);
// produces two PV B-operand fragments via cvt_pk + half-swap shuffle.
// MASKED variant only instantiated for diagonal tiles (wave-uniform branch).
// ---------------------------------------------------------------------------
template<bool MASKED>
__device__ __forceinline__ void softmax_kb(
    const f32x16& st, int kgbase, int q, int ht, float& lsum,
    bf16x8& pf0, bf16x8& pf1)
{
    float pv[16];
#pragma unroll
    for (int r = 0; r < 16; ++r) {
        float sv = st[r];
        if (MASKED) {
            const int kg = kgbase + (r & 3) + 8 * (r >> 2);
            if (kg > q) sv = -1e30f;
        }
        const float p = exp2f(sv);
        pv[r] = p;
        lsum += p;
    }
#pragma unroll
    for (int a = 0; a < 2; ++a) {
        unsigned int u  = cvtpk(pv[8 * a + 0], pv[8 * a + 1]);
        unsigned int u2 = cvtpk(pv[8 * a + 2], pv[8 * a + 3]);
        unsigned int v  = cvtpk(pv[8 * a + 4], pv[8 * a + 5]);
        unsigned int v2 = cvtpk(pv[8 * a + 6], pv[8 * a + 7]);
        int r1 = __shfl_xor((int)(ht ? u : v), 32, 64);
        int r2 = __shfl_xor((int)(ht ? u2 : v2), 32, 64);
        i32x4 w;
        w.x = ht ? r1 : (int)u;
        w.y = ht ? r2 : (int)u2;
        w.z = ht ? (int)v : r1;
        w.w = ht ? (int)v2 : r2;
        (a ? pf1 : pf0) = __builtin_bit_cast(bf16x8, w);
    }
}

// ---------------------------------------------------------------------------
// Kernel 2: causal flash attention, 32x32 swapped-QK^T, in-register P.
// Round-7 change: kfA prefetch VMCNT-FIFO FIX.
//  - R6's kfA prefetch was issued AFTER the 4 gl2lds STAGE ops; vmcnt is a
//    single in-order FIFO counter, so next-iter QK-A waiting on kfA
//    (vmcnt<=4) transitively waited for the STAGE DMA to land — putting
//    staging latency back on the QK critical path every tile (the -6%).
//    FIX: issue kfA BEFORE STAGE. kfA is then the oldest in-flight group
//    and QK-A's wait (vmcnt<=8) leaves STAGE outstanding. Same fix in the
//    prologue.
//  - masked/unmasked softmax split kept (R6 VALU data: real work removed).
//  - occupancy note: grid 2048x128 = exactly the 8-block/CU residency
//    capacity -> whole grid resident at t=0; tail is structural. Don't
//    chase with re-tiling (R4->R5: +2% occ only).
//  - PV ds_read_b128 8-lane/slot aliasing is the structural LDS floor.
// ---------------------------------------------------------------------------
__global__ __launch_bounds__(128, 4) void attn(
    const u16* __restrict__ Q, const u16* __restrict__ K,
    const u16* __restrict__ Vtg, u16* __restrict__ O)
{
    const int qt64 = 31 - (blockIdx.x >> 6);    // heavy-first
    const int bh = blockIdx.x & 63;             // bid%8==bh%8 -> XCD-local K/V
    const int b = bh >> 4, h = bh & 15;
    const int tid = threadIdx.x;
    const int lane = tid & 63;
    const int wave = tid >> 6;                  // 0..1
    const int c31 = lane & 31;
    const int ht  = lane >> 5;

    const size_t hb = ((size_t)h * 8192 + (size_t)b * 2048) * 64;
    const u16* Qp = Q + hb;
    const u16* Kp = K + hb;
    const u16* Vp = Vtg + (size_t)h * 64 * 8192 + (size_t)b * 2048;

    __shared__ __align__(16) u16 Vt[2][64 * 64];   // [d][key-chunk swizzled]

    // V^T staging (128 threads, 4 gl2lds/tile): thread covers d = vd+16g,
    // slot = tid&7; global chunk = slot ^ (d&7) (= slot ^ (vd&7), g*16%8==0).
    // XOR swizzle on the global-address side; LDS dest lane-linear per wave.
    const int vd = tid >> 3, vslot = tid & 7;
    const int vchunk = vslot ^ (vd & 7);
    const u16* vg = Vp + (size_t)vd * 8192 + vchunk * 8;
    u16* const ldst = (u16*)Vt[0] + vd * 64 + vslot * 8;   // + buf sel later

#define STAGE(BUFSEL, KK)                                                      \
    {                                                                          \
        u16* d_ = ldst + (BUFSEL) * 4096;                                      \
        _Pragma("unroll")                                                      \
        for (int g = 0; g < 4; ++g)                                            \
            gl2lds16(vg + (size_t)g * 16 * 8192 + (KK), d_ + g * 1024);        \
    }

    const int qw = qt64 * 64 + wave * 32;
    const int q  = qw + c31;        // this lane's q-row (same for both halves)

    bf16x8 qf[4];
#pragma unroll
    for (int dm = 0; dm < 4; ++dm)
        qf[dm] = load8(Qp + (size_t)q * 64 + dm * 16 + ht * 8);

    f32x16 od0 = {}, od1 = {};      // O^T accum: d 0..31 / 32..63
    float lsum = 0.f;

    const int nkt = qt64 + 1;

    // prologue: kfA prefetch FIRST (oldest in vmcnt FIFO), then V stage
    bf16x8 kfAn[4];
#pragma unroll
    for (int dm = 0; dm < 4; ++dm)
        kfAn[dm] = load8(Kp + (size_t)c31 * 64 + dm * 16 + ht * 8);
    STAGE(0, 0)

    for (int kt = 0; kt < nkt; ++kt) {
        const int k0 = kt * 64;
        u16* vbuf = Vt[kt & 1];
        // upper key-half (k0+32..k0+63) fully masked? (diagonal tile)
        const bool skipB = (k0 >= qw);          // wave-uniform
        const bool needmask = (k0 + 63 > qw);   // wave-uniform
        bf16x8 pf[4];

        // issue kfB loads first: latency covered by QK-A + softmax-A
        bf16x8 kfB[4];
        if (!skipB) {
#pragma unroll
            for (int dm = 0; dm < 4; ++dm)
                kfB[dm] = load8(Kp + (size_t)(k0 + 32 + c31) * 64 + dm * 16 + ht * 8);
        }

        // QK-A from prefetched registers; its wait (kfA oldest) leaves the
        // STAGE DMA in flight
        f32x16 stA = {};
        __builtin_amdgcn_s_setprio(1);
#pragma unroll
        for (int dm = 0; dm < 4; ++dm)
            stA = __builtin_amdgcn_mfma_f32_32x32x16_bf16(kfAn[dm], qf[dm], stA, 0, 0, 0);
        __builtin_amdgcn_s_setprio(0);

        if (needmask)
            softmax_kb<true >(stA, k0 + 4 * ht, q, ht, lsum, pf[0], pf[1]);
        else
            softmax_kb<false>(stA, 0, q, ht, lsum, pf[0], pf[1]);

        if (!skipB) {
            f32x16 stB = {};
            __builtin_amdgcn_s_setprio(1);
#pragma unroll
            for (int dm = 0; dm < 4; ++dm)
                stB = __builtin_amdgcn_mfma_f32_32x32x16_bf16(kfB[dm], qf[dm], stB, 0, 0, 0);
            __builtin_amdgcn_s_setprio(0);
            if (needmask)
                softmax_kb<true >(stB, k0 + 32 + 4 * ht, q, ht, lsum, pf[2], pf[3]);
            else
                softmax_kb<false>(stB, 0, q, ht, lsum, pf[2], pf[3]);
        }

        // drains stage(kt) (issued one iter ago -> landed) and orders all
        // PV(kt-1) reads of buf[(kt+1)&1] before its overwrite
        __syncthreads();

        if (kt + 1 < nkt) {
            // kfA prefetch for tile kt+1 BEFORE the STAGE ops (vmcnt FIFO:
            // kfA oldest -> next QK-A's wait leaves STAGE in flight); both
            // issued after the barrier so its vmcnt(0) can't stall them
#pragma unroll
            for (int dm = 0; dm < 4; ++dm)
                kfAn[dm] = load8(Kp + (size_t)(k0 + 64 + c31) * 64 + dm * 16 + ht * 8);
            STAGE((kt + 1) & 1, k0 + 64)
        }

        __builtin_amdgcn_s_setprio(1);
#pragma unroll
        for (int km = 0; km < 4; ++km) {
            if (km >= 2 && skipB) continue;     // wave-uniform, static unroll
            const int sl = ((km * 2 + ht) ^ (c31 & 7)) * 8;
            bf16x8 v0 = load8(vbuf + c31 * 64 + sl);
            bf16x8 v1 = load8(vbuf + (32 + c31) * 64 + sl);
            od0 = __builtin_amdgcn_mfma_f32_32x32x16_bf16(v0, pf[km], od0, 0, 0, 0);
            od1 = __builtin_amdgcn_mfma_f32_32x32x16_bf16(v1, pf[km], od1, 0, 0, 0);
        }
        __builtin_amdgcn_s_setprio(0);
    }

    // row-sum: own 32 keys + partner half's 32 keys (same q)
    const float tot = lsum +
        __builtin_bit_cast(float, __shfl_xor(__builtin_bit_cast(int, lsum), 32, 64));
    const float inv = 1.0f / tot;

    const size_t orow = (size_t)(b * 2048 + q) * 1024 + h * 64;
#pragma unroll
    for (int tp = 0; tp < 8; ++tp) {
        const int r = 2 * tp;
        const int d = (r & 3) + 8 * (r >> 2) + 4 * ht;   // even -> u32-aligned
        unsigned int w0 = (unsigned int)f2bf(od0[r] * inv) |
                          ((unsigned int)f2bf(od0[r + 1] * inv) << 16);
        unsigned int w1 = (unsigned int)f2bf(od1[r] * inv) |
                          ((unsigned int)f2bf(od1[r + 1] * inv) << 16);
        *reinterpret_cast<unsigned int*>(const_cast<u16*>(O) + orow + d) = w0;
        *reinterpret_cast<unsigned int*>(const_cast<u16*>(O) + orow + 32 + d) = w1;
    }
#undef STAGE
}

// ---------------------------------------------------------------------------
// ws (88 MB): Q 16 | K 16 | Vt 16 | A2 16 | Xb 16 | Wqb 6 | Wpb 2
// ---------------------------------------------------------------------------
extern "C" void kernel_launch(void* const* d_in, const int* in_sizes, int n_in,
                              void* d_out, int out_size, void* d_ws, size_t ws_size,
                              hipStream_t stream) {
    const float* x      = (const float*)d_in[0];
    const float* w_qkv  = (const float*)d_in[1];
    const float* w_proj = (const float*)d_in[2];
    const float* b_proj = (const float*)d_in[3];
    float* out = (float*)d_out;

    u16* Q   = (u16*)d_ws;
    u16* K   = Q   + (size_t)16 * 8192 * 64;
    u16* Vt  = K   + (size_t)16 * 8192 * 64;       // [16][64][8192]
    u16* A2  = Vt  + (size_t)16 * 64 * 8192;
    u16* Xb  = A2  + (size_t)8192 * 1024;
    u16* Wqb = Xb  + (size_t)8192 * 1024;
    u16* Wpb = Wqb + (size_t)3072 * 1024;

    cast_f32_bf16<<<dim3(8192), 256, 0, stream>>>(x, Xb, 8192 * 1024 / 4);
    cast_f32_bf16<<<dim3(3072), 256, 0, stream>>>(w_qkv, Wqb, 3072 * 1024 / 4);
    cast_f32_bf16<<<dim3(1024), 256, 0, stream>>>(w_proj, Wpb, 1024 * 1024 / 4);

    qkv_gemm128<<<dim3(64, 24), 256, 0, stream>>>(Xb, Wqb, Q, K, Vt);
    attn<<<dim3(2048), 128, 0, stream>>>(Q, K, Vt, A2);
    proj_gemm128<<<dim3(64, 8), 256, 0, stream>>>(A2, Wpb, b_proj, out);
}

// Round 9
// 289.852 us; speedup vs baseline: 1.0247x; 1.0247x over previous
//
#include <hip/hip_runtime.h>
#include <hip/hip_bf16.h>

typedef __attribute__((ext_vector_type(8))) short bf16x8;
typedef __attribute__((ext_vector_type(4))) float f32x4;
typedef __attribute__((ext_vector_type(16))) float f32x16;
typedef __attribute__((ext_vector_type(4))) int i32x4;
typedef unsigned short u16;

__device__ __forceinline__ u16 f2bf(float f) {
    __hip_bfloat16 h = __float2bfloat16(f);
    return __builtin_bit_cast(u16, h);
}
__device__ __forceinline__ bf16x8 load8(const u16* p) {
    return *reinterpret_cast<const bf16x8*>(p);
}
__device__ __forceinline__ void gl2lds16(const u16* g, u16* l) {
    __builtin_amdgcn_global_load_lds(
        (const __attribute__((address_space(1))) void*)g,
        (__attribute__((address_space(3))) void*)l, 16, 0, 0);
}
// v_cvt_pk_bf16_f32: low16 = bf16(lo), high16 = bf16(hi)
__device__ __forceinline__ unsigned int cvtpk(float lo, float hi) {
    unsigned int r;
    asm("v_cvt_pk_bf16_f32 %0, %1, %2" : "=v"(r) : "v"(lo), "v"(hi));
    return r;
}

// log2(e)/8: folded into Q so softmax is exp2(s) with no per-element mul
#define QSCALE 0.1803368801111244f

// ---------------------------------------------------------------------------
__global__ __launch_bounds__(256) void cast_f32_bf16(
    const float* __restrict__ src, u16* __restrict__ dst, int n4)
{
    int i = blockIdx.x * blockDim.x + threadIdx.x;
    if (i < n4) {
        float4 f = reinterpret_cast<const float4*>(src)[i];
        ushort4 o;
        o.x = f2bf(f.x); o.y = f2bf(f.y); o.z = f2bf(f.z); o.w = f2bf(f.w);
        reinterpret_cast<ushort4*>(dst)[i] = o;
    }
}

// ---------------------------------------------------------------------------
// m97-style 128x128 GEMM core (bf16, B^T layout W[n][k]).
// As/Bs pointers must be declared by the caller (into its own smem).
// ---------------------------------------------------------------------------
#define GEMM128_BODY(EPILOGUE)                                                 \
    const int t = threadIdx.x;                                                 \
    const int lane = t & 63;                                                   \
    const int wave = t >> 6;                                                   \
    const int quad = lane >> 4;                                                \
    const int lid  = lane & 15;                                                \
    const int wrow = wave & 1;                                                 \
    const int wcol = wave >> 1;                                                \
    const int mtile = blockIdx.x * 128;                                        \
    const int ntile = blockIdx.y * 128;                                        \
    const int srow = t >> 2;                                                   \
    const int scol = (t & 3) * 8;                                              \
    const u16* ga0 = Aptr + (size_t)(mtile + srow) * 1024 + scol;              \
    const u16* ga1 = Aptr + (size_t)(mtile + 64 + srow) * 1024 + scol;         \
    const u16* gb0 = Bptr + (size_t)(ntile + srow) * 1024 + scol;              \
    const u16* gb1 = Bptr + (size_t)(ntile + 64 + srow) * 1024 + scol;         \
    u16* la0 = As + t * 8;                                                     \
    u16* la1 = As + (256 + t) * 8;                                             \
    u16* lb0 = Bs + t * 8;                                                     \
    u16* lb1 = Bs + (256 + t) * 8;                                             \
    f32x4 acc[4][4] = {};                                                      \
    const int aro = wrow * 64 * 32 + quad * 8;                                 \
    const int bro = wcol * 64 * 32 + quad * 8;                                 \
    for (int k0 = 0; k0 < 1024; k0 += 32) {                                    \
        __syncthreads();                                                       \
        gl2lds16(ga0 + k0, la0);                                               \
        gl2lds16(ga1 + k0, la1);                                               \
        gl2lds16(gb0 + k0, lb0);                                               \
        gl2lds16(gb1 + k0, lb1);                                               \
        __syncthreads();                                                       \
        bf16x8 a[4], b[4];                                                     \
        _Pragma("unroll")                                                      \
        for (int i = 0; i < 4; ++i) {                                          \
            a[i] = load8(As + aro + (i * 16 + lid) * 32);                      \
            b[i] = load8(Bs + bro + (i * 16 + lid) * 32);                      \
        }                                                                      \
        _Pragma("unroll")                                                      \
        for (int mi = 0; mi < 4; ++mi)                                         \
            _Pragma("unroll")                                                  \
            for (int ni = 0; ni < 4; ++ni)                                     \
                acc[mi][ni] = __builtin_amdgcn_mfma_f32_16x16x32_bf16(         \
                    a[mi], b[ni], acc[mi][ni], 0, 0, 0);                       \
    }                                                                          \
    EPILOGUE

// ---------------------------------------------------------------------------
// Kernel 1: QKV projection.  Q (pre-scaled by QSCALE), K -> [16][8192][64];
// V transposed -> Vt[16][64][8192].
// Vt writes routed through an LDS transpose tile. The direct path wrote
// 2B/lane at 16KB row stride (8B fragments per lane) — partial-line HBM
// write amplification. Now: stash V accs in smem[64 d][130 m] (pad 130 ->
// conflict-free: dword stride 65 ≡ 1 mod 32), barrier, then the 4 waves
// write rows d = wave+4k (16 rows each) as 64-lane x u32 = 256B contiguous
// segments.  (R8 bug: stride was 8 -> rows d%8>=4 never written.)
// A block's V-columns form a single <=64-wide run (two runs are 192 apart,
// window is 128), so d uniquely indexes the tile and the run's h is found
// per-d by solving ntile <= h*192+128+d < ntile+128.
// ---------------------------------------------------------------------------
__global__ __launch_bounds__(256) void qkv_gemm128(
    const u16* __restrict__ Aptr, const u16* __restrict__ Bptr,
    u16* __restrict__ Q, u16* __restrict__ K, u16* __restrict__ Vt)
{
    __shared__ __align__(16) u16 smem[8320];   // As(4096) Bs(4096); Vs 64x130
    u16* const As = smem;
    u16* const Bs = smem + 4096;
    GEMM128_BODY(
    __syncthreads();   // all waves done with As/Bs ds_reads before reuse
    _Pragma("unroll")
    for (int mi = 0; mi < 4; ++mi)
        _Pragma("unroll")
        for (int ni = 0; ni < 4; ++ni)
            _Pragma("unroll")
            for (int r = 0; r < 4; ++r) {
                int ml = wrow * 64 + mi * 16 + quad * 4 + r;
                int m = mtile + ml;
                int n = ntile + wcol * 64 + ni * 16 + lid;
                int h = n / 192;
                int rr = n - h * 192;
                int sel = rr >> 6;
                int d = rr & 63;
                float v = acc[mi][ni][r];
                if (sel == 2)
                    smem[d * 130 + ml] = f2bf(v);
                else if (sel == 0)
                    Q[((size_t)h * 8192 + m) * 64 + d] = f2bf(v * QSCALE);
                else
                    K[((size_t)h * 8192 + m) * 64 + d] = f2bf(v);
            }
    __syncthreads();
    for (int d = wave; d < 64; d += 4) {          // 4 waves x 16 rows
        int lo = ntile - 128 - d;                 // h*192 >= lo
        int hh = (lo + 191) / 192;                // lo >= -191 -> safe
        int n2 = hh * 192 + 128 + d;
        if (n2 >= ntile && n2 < ntile + 128 && hh < 16) {
            unsigned int w = (unsigned int)smem[d * 130 + lane * 2]
                           | ((unsigned int)smem[d * 130 + lane * 2 + 1] << 16);
            *reinterpret_cast<unsigned int*>(
                Vt + ((size_t)(hh * 64 + d)) * 8192 + mtile + lane * 2) = w;
        }
    }
    )
}

// ---------------------------------------------------------------------------
// Kernel 3: output projection, fp32 out + bias
// ---------------------------------------------------------------------------
__global__ __launch_bounds__(256) void proj_gemm128(
    const u16* __restrict__ Aptr, const u16* __restrict__ Bptr,
    const float* __restrict__ bias, float* __restrict__ out)
{
    __shared__ __align__(16) u16 smem[8192];
    u16* const As = smem;
    u16* const Bs = smem + 4096;
    GEMM128_BODY(
    _Pragma("unroll")
    for (int mi = 0; mi < 4; ++mi)
        _Pragma("unroll")
        for (int ni = 0; ni < 4; ++ni)
            _Pragma("unroll")
            for (int r = 0; r < 4; ++r) {
                int m = mtile + wrow * 64 + mi * 16 + quad * 4 + r;
                int n = ntile + wcol * 64 + ni * 16 + lid;
                out[(size_t)m * 1024 + n] = acc[mi][ni][r] + bias[n];
            }
    )
}

// ---------------------------------------------------------------------------
// Kernel 2: causal flash attention, 32x32 swapped-QK^T, in-register P.
// EXACT Round-5 code (proven 104.5 us).
//  - block = 128 threads (2 waves), 64 q-rows; grid = 2048 = 64 bh x 32
//    qtiles, heavy-first.
//  - S^T = mfma(K,Q) 32x32x16: lane holds a key-column for ONE q-row ->
//    softmax = pure per-lane VALU (32 exp2), ONE shfl_xor(32) at epilogue.
//  - P -> PV B-operand in-register: cvt_pk bf16 pairs + one half-swap
//    shuffle per pair. No Ps LDS round-trip.
//  - V LDS-staged via gl2lds (direct-global V gather fatal in R2),
//    XOR-swizzled on the global-address side, double-buffered, prefetched
//    one tile ahead. K direct-global (L1/L2-resident per block).
//  - skipB: wave-uniform skip of fully-masked upper key-half on diagonal.
// ---------------------------------------------------------------------------
__global__ __launch_bounds__(128, 4) void attn(
    const u16* __restrict__ Q, const u16* __restrict__ K,
    const u16* __restrict__ Vtg, u16* __restrict__ O)
{
    const int qt64 = 31 - (blockIdx.x >> 6);    // heavy-first
    const int bh = blockIdx.x & 63;             // bid%8==bh%8 -> XCD-local K/V
    const int b = bh >> 4, h = bh & 15;
    const int tid = threadIdx.x;
    const int lane = tid & 63;
    const int wave = tid >> 6;                  // 0..1
    const int c31 = lane & 31;
    const int ht  = lane >> 5;

    const size_t hb = ((size_t)h * 8192 + (size_t)b * 2048) * 64;
    const u16* Qp = Q + hb;
    const u16* Kp = K + hb;
    const u16* Vp = Vtg + (size_t)h * 64 * 8192 + (size_t)b * 2048;

    __shared__ __align__(16) u16 Vt[2][64 * 64];   // [d][key-chunk swizzled]

    // V^T staging (128 threads, 4 gl2lds/tile): thread covers d = vd+16g,
    // slot = tid&7; global chunk = slot ^ (d&7) (= slot ^ (vd&7), g*16%8==0).
    // XOR swizzle on the global-address side; LDS dest lane-linear per wave.
    const int vd = tid >> 3, vslot = tid & 7;
    const int vchunk = vslot ^ (vd & 7);
    const u16* vg = Vp + (size_t)vd * 8192 + vchunk * 8;
    u16* const ldst = (u16*)Vt[0] + vd * 64 + vslot * 8;   // + buf sel later

#define STAGE(BUFSEL, KK)                                                      \
    {                                                                          \
        u16* d_ = ldst + (BUFSEL) * 4096;                                      \
        _Pragma("unroll")                                                      \
        for (int g = 0; g < 4; ++g)                                            \
            gl2lds16(vg + (size_t)g * 16 * 8192 + (KK), d_ + g * 1024);        \
    }

    const int qw = qt64 * 64 + wave * 32;
    const int q  = qw + c31;        // this lane's q-row (same for both halves)

    bf16x8 qf[4];
#pragma unroll
    for (int dm = 0; dm < 4; ++dm)
        qf[dm] = load8(Qp + (size_t)q * 64 + dm * 16 + ht * 8);

    f32x16 od0 = {}, od1 = {};      // O^T accum: d 0..31 / 32..63
    float lsum = 0.f;

    const int nkt = qt64 + 1;

    // prologue: stage tile 0
    STAGE(0, 0)

#define SOFTMAX_KB(ST, KBOFF, PF0, PF1)                                        \
    {                                                                          \
        float pv[16];                                                          \
        _Pragma("unroll")                                                      \
        for (int r = 0; r < 16; ++r) {                                         \
            const int kg = k0 + (KBOFF) + (r & 3) + 8 * (r >> 2) + 4 * ht;     \
            float sv = ST[r];                                                  \
            if (needmask && kg > q) sv = -1e30f;                               \
            const float p = exp2f(sv);                                         \
            pv[r] = p;                                                         \
            lsum += p;                                                         \
        }                                                                      \
        _Pragma("unroll")                                                      \
        for (int a = 0; a < 2; ++a) {                                          \
            unsigned int u  = cvtpk(pv[8 * a + 0], pv[8 * a + 1]);             \
            unsigned int u2 = cvtpk(pv[8 * a + 2], pv[8 * a + 3]);             \
            unsigned int v  = cvtpk(pv[8 * a + 4], pv[8 * a + 5]);             \
            unsigned int v2 = cvtpk(pv[8 * a + 6], pv[8 * a + 7]);             \
            int r1 = __shfl_xor((int)(ht ? u : v), 32, 64);                    \
            int r2 = __shfl_xor((int)(ht ? u2 : v2), 32, 64);                  \
            i32x4 w;                                                           \
            w.x = ht ? r1 : (int)u;                                            \
            w.y = ht ? r2 : (int)u2;                                           \
            w.z = ht ? (int)v : r1;                                            \
            w.w = ht ? (int)v2 : r2;                                           \
            ((a) ? (PF1) : (PF0)) = __builtin_bit_cast(bf16x8, w);             \
        }                                                                      \
    }

    for (int kt = 0; kt < nkt; ++kt) {
        const int k0 = kt * 64;
        u16* vbuf = Vt[kt & 1];
        // upper key-half (k0+32..k0+63) fully masked? (wave0 diagonal tile)
        const bool skipB = (k0 >= qw);          // wave-uniform
        const bool needmask = (k0 + 63 > qw);   // wave-uniform
        bf16x8 pf[4];

        {
            bf16x8 kfA[4];
#pragma unroll
            for (int dm = 0; dm < 4; ++dm)
                kfA[dm] = load8(Kp + (size_t)(k0 + c31) * 64 + dm * 16 + ht * 8);
            f32x16 stA = {};
            __builtin_amdgcn_s_setprio(1);
#pragma unroll
            for (int dm = 0; dm < 4; ++dm)
                stA = __builtin_amdgcn_mfma_f32_32x32x16_bf16(kfA[dm], qf[dm], stA, 0, 0, 0);
            __builtin_amdgcn_s_setprio(0);
            SOFTMAX_KB(stA, 0, pf[0], pf[1]);
        }
        if (!skipB) {
            bf16x8 kfB[4];
#pragma unroll
            for (int dm = 0; dm < 4; ++dm)
                kfB[dm] = load8(Kp + (size_t)(k0 + 32 + c31) * 64 + dm * 16 + ht * 8);
            f32x16 stB = {};
            __builtin_amdgcn_s_setprio(1);
#pragma unroll
            for (int dm = 0; dm < 4; ++dm)
                stB = __builtin_amdgcn_mfma_f32_32x32x16_bf16(kfB[dm], qf[dm], stB, 0, 0, 0);
            __builtin_amdgcn_s_setprio(0);
            SOFTMAX_KB(stB, 32, pf[2], pf[3]);
        }

        // drains stage(kt) (issued one iter ago -> landed) and orders all
        // PV(kt-1) reads of buf[(kt+1)&1] before its overwrite
        __syncthreads();

        if (kt + 1 < nkt) STAGE((kt + 1) & 1, k0 + 64)

        __builtin_amdgcn_s_setprio(1);
#pragma unroll
        for (int km = 0; km < 4; ++km) {
            if (km >= 2 && skipB) continue;     // wave-uniform, static unroll
            const int sl = ((km * 2 + ht) ^ (c31 & 7)) * 8;
            bf16x8 v0 = load8(vbuf + c31 * 64 + sl);
            bf16x8 v1 = load8(vbuf + (32 + c31) * 64 + sl);
            od0 = __builtin_amdgcn_mfma_f32_32x32x16_bf16(v0, pf[km], od0, 0, 0, 0);
            od1 = __builtin_amdgcn_mfma_f32_32x32x16_bf16(v1, pf[km], od1, 0, 0, 0);
        }
        __builtin_amdgcn_s_setprio(0);
    }

    // row-sum: own 32 keys + partner half's 32 keys (same q)
    const float tot = lsum +
        __builtin_bit_cast(float, __shfl_xor(__builtin_bit_cast(int, lsum), 32, 64));
    const float inv = 1.0f / tot;

    const size_t orow = (size_t)(b * 2048 + q) * 1024 + h * 64;
#pragma unroll
    for (int tp = 0; tp < 8; ++tp) {
        const int r = 2 * tp;
        const int d = (r & 3) + 8 * (r >> 2) + 4 * ht;   // even -> u32-aligned
        unsigned int w0 = (unsigned int)f2bf(od0[r] * inv) |
                          ((unsigned int)f2bf(od0[r + 1] * inv) << 16);
        unsigned int w1 = (unsigned int)f2bf(od1[r] * inv) |
                          ((unsigned int)f2bf(od1[r + 1] * inv) << 16);
        *reinterpret_cast<unsigned int*>(const_cast<u16*>(O) + orow + d) = w0;
        *reinterpret_cast<unsigned int*>(const_cast<u16*>(O) + orow + 32 + d) = w1;
    }
#undef SOFTMAX_KB
#undef STAGE
}

// ---------------------------------------------------------------------------
// ws (88 MB): Q 16 | K 16 | Vt 16 | A2 16 | Xb 16 | Wqb 6 | Wpb 2
// ---------------------------------------------------------------------------
extern "C" void kernel_launch(void* const* d_in, const int* in_sizes, int n_in,
                              void* d_out, int out_size, void* d_ws, size_t ws_size,
                              hipStream_t stream) {
    const float* x      = (const float*)d_in[0];
    const float* w_qkv  = (const float*)d_in[1];
    const float* w_proj = (const float*)d_in[2];
    const float* b_proj = (const float*)d_in[3];
    float* out = (float*)d_out;

    u16* Q   = (u16*)d_ws;
    u16* K   = Q   + (size_t)16 * 8192 * 64;
    u16* Vt  = K   + (size_t)16 * 8192 * 64;       // [16][64][8192]
    u16* A2  = Vt  + (size_t)16 * 64 * 8192;
    u16* Xb  = A2  + (size_t)8192 * 1024;
    u16* Wqb = Xb  + (size_t)8192 * 1024;
    u16* Wpb = Wqb + (size_t)3072 * 1024;

    cast_f32_bf16<<<dim3(8192), 256, 0, stream>>>(x, Xb, 8192 * 1024 / 4);
    cast_f32_bf16<<<dim3(3072), 256, 0, stream>>>(w_qkv, Wqb, 3072 * 1024 / 4);
    cast_f32_bf16<<<dim3(1024), 256, 0, stream>>>(w_proj, Wpb, 1024 * 1024 / 4);

    qkv_gemm128<<<dim3(64, 24), 256, 0, stream>>>(Xb, Wqb, Q, K, Vt);
    attn<<<dim3(2048), 128, 0, stream>>>(Q, K, Vt, A2);
    proj_gemm128<<<dim3(64, 8), 256, 0, stream>>>(A2, Wpb, b_proj, out);
}

// Round 10
// 278.312 us; speedup vs baseline: 1.0672x; 1.0415x over previous
//
#include <hip/hip_runtime.h>
#include <hip/hip_bf16.h>

typedef __attribute__((ext_vector_type(8))) short bf16x8;
typedef __attribute__((ext_vector_type(4))) float f32x4;
typedef __attribute__((ext_vector_type(16))) float f32x16;
typedef __attribute__((ext_vector_type(4))) int i32x4;
typedef unsigned short u16;

__device__ __forceinline__ u16 f2bf(float f) {
    __hip_bfloat16 h = __float2bfloat16(f);
    return __builtin_bit_cast(u16, h);
}
__device__ __forceinline__ bf16x8 load8(const u16* p) {
    return *reinterpret_cast<const bf16x8*>(p);
}
__device__ __forceinline__ void gl2lds16(const u16* g, u16* l) {
    __builtin_amdgcn_global_load_lds(
        (const __attribute__((address_space(1))) void*)g,
        (__attribute__((address_space(3))) void*)l, 16, 0, 0);
}
// v_cvt_pk_bf16_f32: low16 = bf16(lo), high16 = bf16(hi)
__device__ __forceinline__ unsigned int cvtpk(float lo, float hi) {
    unsigned int r;
    asm("v_cvt_pk_bf16_f32 %0, %1, %2" : "=v"(r) : "v"(lo), "v"(hi));
    return r;
}

// log2(e)/8: folded into Q so softmax is exp2(s) with no per-element mul
#define QSCALE 0.1803368801111244f

// ---------------------------------------------------------------------------
// Merged cast kernel: x (2097152 f4) | w_qkv (786432 f4) | w_proj (262144 f4)
// ---------------------------------------------------------------------------
__global__ __launch_bounds__(256) void cast_all(
    const float* __restrict__ x, const float* __restrict__ wq,
    const float* __restrict__ wp, u16* __restrict__ Xb,
    u16* __restrict__ Wqb, u16* __restrict__ Wpb)
{
    int i = blockIdx.x * blockDim.x + threadIdx.x;
    const float* s; u16* d; int j;
    if (i < 2097152)      { s = x;  d = Xb;  j = i; }
    else if (i < 2883584) { s = wq; d = Wqb; j = i - 2097152; }
    else                  { s = wp; d = Wpb; j = i - 2883584; }
    float4 f = reinterpret_cast<const float4*>(s)[j];
    ushort4 o;
    o.x = f2bf(f.x); o.y = f2bf(f.y); o.z = f2bf(f.z); o.w = f2bf(f.w);
    reinterpret_cast<ushort4*>(d)[j] = o;
}

// ---------------------------------------------------------------------------
// 256x128-tile GEMM core (bf16, B^T layout W[n][k], K=1024, BK=64).
// 512 threads = 8 waves (4M x 2N), per-wave 64x64 out (4x4 frags, 2 k-halves).
// LDS per buffer (u16 offsets): A plane0 [0,8192) rows 256 x k 0..31;
//   A plane1 [8192,16384); B plane0 [16384,20480) rows 128; B plane1 [20480,24576).
// Double-buffered: STAGE(ks+1) issued AFTER the barrier (so the barrier only
// drains the one-iteration-old stage = landed), consumed next iteration.
// k-half planes keep the ds_read row stride at 64B (m97's 8-way, not 16-way).
// Dynamic LDS: 2 x 24576 u16 = 96 KB -> 1 block/CU.
// ---------------------------------------------------------------------------
#define GEMM256_BODY(EPILOGUE)                                                 \
    const int t = threadIdx.x;                                                 \
    const int lane = t & 63;                                                   \
    const int wave = t >> 6;                                                   \
    const int quad = (lane >> 4);                                              \
    const int lid  = lane & 15;                                                \
    const int wm = wave >> 1;                                                  \
    const int wn = wave & 1;                                                   \
    const int mtile = blockIdx.x * 256;                                        \
    const int ntile = blockIdx.y * 128;                                        \
    const int srow = t >> 2;                                                   \
    const int sk   = (t & 3) * 8;                                              \
    const u16* gA0 = Aptr + (size_t)(mtile + srow) * 1024 + sk;                \
    const u16* gA1 = Aptr + (size_t)(mtile + 128 + srow) * 1024 + sk;          \
    const u16* gA2 = gA0 + 32;                                                 \
    const u16* gA3 = gA1 + 32;                                                 \
    const u16* gB0 = Bptr + (size_t)(ntile + srow) * 1024 + sk;                \
    const u16* gB1 = gB0 + 32;                                                 \
    f32x4 acc[4][4] = {};                                                      \
    STAGE_G(smem, 0)                                                           \
    for (int ks = 0; ks < 16; ++ks) {                                          \
        u16* cb = smem + (ks & 1) * 24576;                                     \
        __syncthreads();                                                       \
        if (ks + 1 < 16) {                                                     \
            u16* nb = smem + ((ks + 1) & 1) * 24576;                           \
            STAGE_G(nb, (ks + 1) * 64)                                         \
        }                                                                      \
        bf16x8 af[4][2], bfr[4][2];                                            \
        _Pragma("unroll")                                                      \
        for (int mi = 0; mi < 4; ++mi)                                         \
            _Pragma("unroll")                                                  \
            for (int kh = 0; kh < 2; ++kh)                                     \
                af[mi][kh] = load8(cb + kh * 8192 +                            \
                    (wm * 64 + mi * 16 + lid) * 32 + quad * 8);                \
        _Pragma("unroll")                                                      \
        for (int ni = 0; ni < 4; ++ni)                                         \
            _Pragma("unroll")                                                  \
            for (int kh = 0; kh < 2; ++kh)                                     \
                bfr[ni][kh] = load8(cb + 16384 + kh * 4096 +                   \
                    (wn * 64 + ni * 16 + lid) * 32 + quad * 8);                \
        __builtin_amdgcn_s_setprio(1);                                         \
        _Pragma("unroll")                                                      \
        for (int mi = 0; mi < 4; ++mi)                                         \
            _Pragma("unroll")                                                  \
            for (int ni = 0; ni < 4; ++ni) {                                   \
                acc[mi][ni] = __builtin_amdgcn_mfma_f32_16x16x32_bf16(         \
                    af[mi][0], bfr[ni][0], acc[mi][ni], 0, 0, 0);              \
                acc[mi][ni] = __builtin_amdgcn_mfma_f32_16x16x32_bf16(         \
                    af[mi][1], bfr[ni][1], acc[mi][ni], 0, 0, 0);              \
            }                                                                  \
        __builtin_amdgcn_s_setprio(0);                                         \
    }                                                                          \
    EPILOGUE

#define STAGE_G(BASE, KK)                                                      \
    {                                                                          \
        gl2lds16(gA0 + (KK), (BASE) + t * 8);                                  \
        gl2lds16(gA1 + (KK), (BASE) + 4096 + t * 8);                           \
        gl2lds16(gA2 + (KK), (BASE) + 8192 + t * 8);                           \
        gl2lds16(gA3 + (KK), (BASE) + 12288 + t * 8);                          \
        gl2lds16(gB0 + (KK), (BASE) + 16384 + t * 8);                          \
        gl2lds16(gB1 + (KK), (BASE) + 20480 + t * 8);                          \
    }

// ---------------------------------------------------------------------------
// Kernel 1: QKV projection.  Q (pre-scaled by QSCALE), K -> [16][8192][64];
// V transposed -> Vt[16][64][8192] via an LDS transpose tile (reuses the
// staging LDS after the K-loop; 64 d x 258 m, dword stride 129 = 1 mod 32 ->
// conflict-free).  A block's n-window is 128 wide, so its V-columns form a
// single <=64-wide run (runs are 192 apart): d uniquely indexes the tile and
// the run's h solves ntile <= h*192+128+d < ntile+128.
// ---------------------------------------------------------------------------
__global__ __launch_bounds__(512, 2) void qkv_gemm256(
    const u16* __restrict__ Aptr, const u16* __restrict__ Bptr,
    u16* __restrict__ Q, u16* __restrict__ K, u16* __restrict__ Vt)
{
    extern __shared__ u16 smem[];
    GEMM256_BODY(
    __syncthreads();   // all waves done with staging-LDS ds_reads before reuse
    _Pragma("unroll")
    for (int mi = 0; mi < 4; ++mi)
        _Pragma("unroll")
        for (int ni = 0; ni < 4; ++ni)
            _Pragma("unroll")
            for (int r = 0; r < 4; ++r) {
                int ml = wm * 64 + mi * 16 + quad * 4 + r;
                int m = mtile + ml;
                int n = ntile + wn * 64 + ni * 16 + lid;
                int h = n / 192;
                int rr = n - h * 192;
                int sel = rr >> 6;
                int d = rr & 63;
                float v = acc[mi][ni][r];
                if (sel == 2)
                    smem[d * 258 + ml] = f2bf(v);
                else if (sel == 0)
                    Q[((size_t)h * 8192 + m) * 64 + d] = f2bf(v * QSCALE);
                else
                    K[((size_t)h * 8192 + m) * 64 + d] = f2bf(v);
            }
    __syncthreads();
    for (int d = wave; d < 64; d += 8) {          // 8 waves x 8 rows
        int lo = ntile - 128 - d;                 // h*192 >= lo
        int hh = (lo + 191) / 192;                // lo >= -191 -> safe
        int n2 = hh * 192 + 128 + d;
        if (n2 >= ntile && n2 < ntile + 128 && hh < 16) {
            _Pragma("unroll")
            for (int p = 0; p < 2; ++p) {
                int idx = lane + p * 64;          // m-pair index 0..127
                unsigned int w = (unsigned int)smem[d * 258 + idx * 2]
                               | ((unsigned int)smem[d * 258 + idx * 2 + 1] << 16);
                *reinterpret_cast<unsigned int*>(
                    Vt + ((size_t)(hh * 64 + d)) * 8192 + mtile + idx * 2) = w;
            }
        }
    }
    )
}

// ---------------------------------------------------------------------------
// Kernel 3: output projection, fp32 out + bias
// ---------------------------------------------------------------------------
__global__ __launch_bounds__(512, 2) void proj_gemm256(
    const u16* __restrict__ Aptr, const u16* __restrict__ Bptr,
    const float* __restrict__ bias, float* __restrict__ out)
{
    extern __shared__ u16 smem[];
    GEMM256_BODY(
    _Pragma("unroll")
    for (int mi = 0; mi < 4; ++mi)
        _Pragma("unroll")
        for (int ni = 0; ni < 4; ++ni)
            _Pragma("unroll")
            for (int r = 0; r < 4; ++r) {
                int m = mtile + wm * 64 + mi * 16 + quad * 4 + r;
                int n = ntile + wn * 64 + ni * 16 + lid;
                out[(size_t)m * 1024 + n] = acc[mi][ni][r] + bias[n];
            }
    )
}

// ---------------------------------------------------------------------------
// Kernel 2: causal flash attention, 32x32 swapped-QK^T, in-register P.
// EXACT Round-5 code (proven 104.5 us).
// ---------------------------------------------------------------------------
__global__ __launch_bounds__(128, 4) void attn(
    const u16* __restrict__ Q, const u16* __restrict__ K,
    const u16* __restrict__ Vtg, u16* __restrict__ O)
{
    const int qt64 = 31 - (blockIdx.x >> 6);    // heavy-first
    const int bh = blockIdx.x & 63;             // bid%8==bh%8 -> XCD-local K/V
    const int b = bh >> 4, h = bh & 15;
    const int tid = threadIdx.x;
    const int lane = tid & 63;
    const int wave = tid >> 6;                  // 0..1
    const int c31 = lane & 31;
    const int ht  = lane >> 5;

    const size_t hb = ((size_t)h * 8192 + (size_t)b * 2048) * 64;
    const u16* Qp = Q + hb;
    const u16* Kp = K + hb;
    const u16* Vp = Vtg + (size_t)h * 64 * 8192 + (size_t)b * 2048;

    __shared__ __align__(16) u16 Vt[2][64 * 64];   // [d][key-chunk swizzled]

    // V^T staging (128 threads, 4 gl2lds/tile): thread covers d = vd+16g,
    // slot = tid&7; global chunk = slot ^ (d&7).  XOR swizzle on the
    // global-address side; LDS dest lane-linear per wave.
    const int vd = tid >> 3, vslot = tid & 7;
    const int vchunk = vslot ^ (vd & 7);
    const u16* vg = Vp + (size_t)vd * 8192 + vchunk * 8;
    u16* const ldst = (u16*)Vt[0] + vd * 64 + vslot * 8;   // + buf sel later

#define STAGE(BUFSEL, KK)                                                      \
    {                                                                          \
        u16* d_ = ldst + (BUFSEL) * 4096;                                      \
        _Pragma("unroll")                                                      \
        for (int g = 0; g < 4; ++g)                                            \
            gl2lds16(vg + (size_t)g * 16 * 8192 + (KK), d_ + g * 1024);        \
    }

    const int qw = qt64 * 64 + wave * 32;
    const int q  = qw + c31;        // this lane's q-row (same for both halves)

    bf16x8 qf[4];
#pragma unroll
    for (int dm = 0; dm < 4; ++dm)
        qf[dm] = load8(Qp + (size_t)q * 64 + dm * 16 + ht * 8);

    f32x16 od0 = {}, od1 = {};      // O^T accum: d 0..31 / 32..63
    float lsum = 0.f;

    const int nkt = qt64 + 1;

    // prologue: stage tile 0
    STAGE(0, 0)

#define SOFTMAX_KB(ST, KBOFF, PF0, PF1)                                        \
    {                                                                          \
        float pv[16];                                                          \
        _Pragma("unroll")                                                      \
        for (int r = 0; r < 16; ++r) {                                         \
            const int kg = k0 + (KBOFF) + (r & 3) + 8 * (r >> 2) + 4 * ht;     \
            float sv = ST[r];                                                  \
            if (needmask && kg > q) sv = -1e30f;                               \
            const float p = exp2f(sv);                                         \
            pv[r] = p;                                                         \
            lsum += p;                                                         \
        }                                                                      \
        _Pragma("unroll")                                                      \
        for (int a = 0; a < 2; ++a) {                                          \
            unsigned int u  = cvtpk(pv[8 * a + 0], pv[8 * a + 1]);             \
            unsigned int u2 = cvtpk(pv[8 * a + 2], pv[8 * a + 3]);             \
            unsigned int v  = cvtpk(pv[8 * a + 4], pv[8 * a + 5]);             \
            unsigned int v2 = cvtpk(pv[8 * a + 6], pv[8 * a + 7]);             \
            int r1 = __shfl_xor((int)(ht ? u : v), 32, 64);                    \
            int r2 = __shfl_xor((int)(ht ? u2 : v2), 32, 64);                  \
            i32x4 w;                                                           \
            w.x = ht ? r1 : (int)u;                                            \
            w.y = ht ? r2 : (int)u2;                                           \
            w.z = ht ? (int)v : r1;                                            \
            w.w = ht ? (int)v2 : r2;                                           \
            ((a) ? (PF1) : (PF0)) = __builtin_bit_cast(bf16x8, w);             \
        }                                                                      \
    }

    for (int kt = 0; kt < nkt; ++kt) {
        const int k0 = kt * 64;
        u16* vbuf = Vt[kt & 1];
        // upper key-half (k0+32..k0+63) fully masked? (wave0 diagonal tile)
        const bool skipB = (k0 >= qw);          // wave-uniform
        const bool needmask = (k0 + 63 > qw);   // wave-uniform
        bf16x8 pf[4];

        {
            bf16x8 kfA[4];
#pragma unroll
            for (int dm = 0; dm < 4; ++dm)
                kfA[dm] = load8(Kp + (size_t)(k0 + c31) * 64 + dm * 16 + ht * 8);
            f32x16 stA = {};
            __builtin_amdgcn_s_setprio(1);
#pragma unroll
            for (int dm = 0; dm < 4; ++dm)
                stA = __builtin_amdgcn_mfma_f32_32x32x16_bf16(kfA[dm], qf[dm], stA, 0, 0, 0);
            __builtin_amdgcn_s_setprio(0);
            SOFTMAX_KB(stA, 0, pf[0], pf[1]);
        }
        if (!skipB) {
            bf16x8 kfB[4];
#pragma unroll
            for (int dm = 0; dm < 4; ++dm)
                kfB[dm] = load8(Kp + (size_t)(k0 + 32 + c31) * 64 + dm * 16 + ht * 8);
            f32x16 stB = {};
            __builtin_amdgcn_s_setprio(1);
#pragma unroll
            for (int dm = 0; dm < 4; ++dm)
                stB = __builtin_amdgcn_mfma_f32_32x32x16_bf16(kfB[dm], qf[dm], stB, 0, 0, 0);
            __builtin_amdgcn_s_setprio(0);
            SOFTMAX_KB(stB, 32, pf[2], pf[3]);
        }

        // drains stage(kt) (issued one iter ago -> landed) and orders all
        // PV(kt-1) reads of buf[(kt+1)&1] before its overwrite
        __syncthreads();

        if (kt + 1 < nkt) STAGE((kt + 1) & 1, k0 + 64)

        __builtin_amdgcn_s_setprio(1);
#pragma unroll
        for (int km = 0; km < 4; ++km) {
            if (km >= 2 && skipB) continue;     // wave-uniform, static unroll
            const int sl = ((km * 2 + ht) ^ (c31 & 7)) * 8;
            bf16x8 v0 = load8(vbuf + c31 * 64 + sl);
            bf16x8 v1 = load8(vbuf + (32 + c31) * 64 + sl);
            od0 = __builtin_amdgcn_mfma_f32_32x32x16_bf16(v0, pf[km], od0, 0, 0, 0);
            od1 = __builtin_amdgcn_mfma_f32_32x32x16_bf16(v1, pf[km], od1, 0, 0, 0);
        }
        __builtin_amdgcn_s_setprio(0);
    }

    // row-sum: own 32 keys + partner half's 32 keys (same q)
    const float tot = lsum +
        __builtin_bit_cast(float, __shfl_xor(__builtin_bit_cast(int, lsum), 32, 64));
    const float inv = 1.0f / tot;

    const size_t orow = (size_t)(b * 2048 + q) * 1024 + h * 64;
#pragma unroll
    for (int tp = 0; tp < 8; ++tp) {
        const int r = 2 * tp;
        const int d = (r & 3) + 8 * (r >> 2) + 4 * ht;   // even -> u32-aligned
        unsigned int w0 = (unsigned int)f2bf(od0[r] * inv) |
                          ((unsigned int)f2bf(od0[r + 1] * inv) << 16);
        unsigned int w1 = (unsigned int)f2bf(od1[r] * inv) |
                          ((unsigned int)f2bf(od1[r + 1] * inv) << 16);
        *reinterpret_cast<unsigned int*>(const_cast<u16*>(O) + orow + d) = w0;
        *reinterpret_cast<unsigned int*>(const_cast<u16*>(O) + orow + 32 + d) = w1;
    }
#undef SOFTMAX_KB
#undef STAGE
}

// ---------------------------------------------------------------------------
// ws (88 MB): Q 16 | K 16 | Vt 16 | A2 16 | Xb 16 | Wqb 6 | Wpb 2
// ---------------------------------------------------------------------------
extern "C" void kernel_launch(void* const* d_in, const int* in_sizes, int n_in,
                              void* d_out, int out_size, void* d_ws, size_t ws_size,
                              hipStream_t stream) {
    const float* x      = (const float*)d_in[0];
    const float* w_qkv  = (const float*)d_in[1];
    const float* w_proj = (const float*)d_in[2];
    const float* b_proj = (const float*)d_in[3];
    float* out = (float*)d_out;

    u16* Q   = (u16*)d_ws;
    u16* K   = Q   + (size_t)16 * 8192 * 64;
    u16* Vt  = K   + (size_t)16 * 8192 * 64;       // [16][64][8192]
    u16* A2  = Vt  + (size_t)16 * 64 * 8192;
    u16* Xb  = A2  + (size_t)8192 * 1024;
    u16* Wqb = Xb  + (size_t)8192 * 1024;
    u16* Wpb = Wqb + (size_t)3072 * 1024;

    cast_all<<<dim3(12288), 256, 0, stream>>>(x, w_qkv, w_proj, Xb, Wqb, Wpb);

    qkv_gemm256<<<dim3(32, 24), 512, 98304, stream>>>(Xb, Wqb, Q, K, Vt);
    attn<<<dim3(2048), 128, 0, stream>>>(Q, K, Vt, A2);
    proj_gemm256<<<dim3(32, 8), 512, 98304, stream>>>(A2, Wpb, b_proj, out);
}